// Round 14
// baseline (207.591 us; speedup 1.0000x reference)
//
#include <hip/hip_runtime.h>
#include <math.h>

// Problem constants
constexpr int Uc = 512;
constexpr int Pc = 1024;
constexpr int Dc = 128;
constexpr int Hc = 256;
constexpr int Ec = 98304;
constexpr int Nc = 1536;   // U + P
constexpr int CAP = 192;   // bucket capacity (deg ~ B(98304,1/1536): mu=64, sigma=8)

__device__ __forceinline__ void fma4(float4& a, float n, const float4 r) {
    a.x += n * r.x; a.y += n * r.y; a.z += n * r.z; a.w += n * r.w;
}

// ---------------- GEMM core: 16 rows x 32 cols / 256-thread block ----------------
template <int K>
__device__ __forceinline__ void gemm_core16(const float* __restrict__ xr,
                                            const float* __restrict__ wc, int M,
                                            float& acc0, float& acc1) {
#pragma unroll 4
    for (int k = 0; k < K; k += 4) {
        float4 a = *(const float4*)(xr + k);
        float2 b0 = *(const float2*)(wc + (size_t)k * M);
        float2 b1 = *(const float2*)(wc + (size_t)(k + 1) * M);
        float2 b2 = *(const float2*)(wc + (size_t)(k + 2) * M);
        float2 b3 = *(const float2*)(wc + (size_t)(k + 3) * M);
        acc0 += a.x * b0.x; acc1 += a.x * b0.y;
        acc0 += a.y * b1.x; acc1 += a.y * b1.y;
        acc0 += a.z * b2.x; acc1 += a.z * b2.y;
        acc0 += a.w * b3.x; acc1 += a.w * b3.y;
    }
}

// ---------------- front kernel: scatter | weight collapse | bias ----------------
__global__ void k_front(const int* __restrict__ e_src, const int* __restrict__ e_dst,
                        int* __restrict__ cnt, int* __restrict__ colF,
                        const float* __restrict__ Wu, const float* __restrict__ Wp,
                        const float* __restrict__ Wq1, const float* __restrict__ bu,
                        const float* __restrict__ bp, const float* __restrict__ bq1,
                        float* __restrict__ Wup, float* __restrict__ Wpp,
                        float* __restrict__ bvu, float* __restrict__ bvp) {
    int t = threadIdx.x, b = blockIdx.x;
    if (b < 384) {
        int e = b * 256 + t;
        int d = e_dst[e];
        int pos = atomicAdd(&cnt[d], 1);
        if (pos < CAP) colF[d * CAP + pos] = e_src[e];
    } else if (b < 640) {
        int id = b - 384;
        int z = id >> 7, tile = id & 127;
        int tx = t & 15, ty = t >> 4;
        const float* X = z ? Wp : Wu;
        const float* W = Wq1 + (z ? (size_t)Dc * Hc : 0);
        float* Y = z ? Wpp : Wup;
        int row = (tile >> 3) * 16 + ty, col = (tile & 7) * 32 + tx * 2;
        float a0 = 0.f, a1 = 0.f;
        gemm_core16<Dc>(X + (size_t)row * Dc, W + col, Hc, a0, a1);
        *(float2*)&Y[(size_t)row * Hc + col] = make_float2(a0, a1);
    } else if (b == 640) {
        float s = bq1[t];
#pragma unroll 8
        for (int d = 0; d < Dc; d++) s += bu[d] * Wq1[d * Hc + t];
        bvu[t] = s;
    } else {
        float s = 0.f;
#pragma unroll 8
        for (int d = 0; d < Dc; d++) s += bp[d] * Wq1[(Dc + d) * Hc + t];
        bvp[t] = s;
    }
}

// ---------------- layer 0: agg(embeddings) @ W0 + b0, relu -> xA ---------------
// 2 nodes / block, 768 blocks. Waves (2r, 2r+1) aggregate node r over neighbor
// halves; lane l -> features 2l..2l+2 (D=128). 8 row-loads in flight per lane.
__global__ void k_l0(const int* __restrict__ uid, const int* __restrict__ pid,
                     const float* __restrict__ ue, const float* __restrict__ pe,
                     const float* __restrict__ W0, const float* __restrict__ b0,
                     const int* __restrict__ cnt, const int* __restrict__ colF,
                     float* __restrict__ out) {
    __shared__ const float* sptr[2][CAP];
    __shared__ float snrm[2][CAP];
    __shared__ __align__(16) float pagg[4][Dc];
    __shared__ __align__(16) float agg[2][Dc];
    int t = threadIdx.x, b = blockIdx.x;
    int ibase = b * 2;
    int c[2]; float di[2];
#pragma unroll
    for (int r = 0; r < 2; r++) {
        c[r] = cnt[ibase + r];
        di[r] = rsqrtf((float)(c[r] + 1));
        int deg = min(c[r], CAP);
        if (t < deg) {
            int s = colF[(ibase + r) * CAP + t];
            sptr[r][t] = (s < Uc) ? ue + (size_t)uid[s] * Dc
                                  : pe + (size_t)pid[s - Uc] * Dc;
            snrm[r][t] = rsqrtf((float)(cnt[s] + 1));
        }
    }
    __syncthreads();
    {   // wave wv: node r = wv>>1, neighbor half h = wv&1
        int wv = t >> 6, ln = t & 63;
        int r = wv >> 1, h = wv & 1;
        int i = ibase + r;
        int dg = min(c[r], CAP);
        int dg2 = dg >> 1;
        int j0 = h ? dg2 : 0, j1 = h ? dg : dg2;
        float2 acc = make_float2(0.f, 0.f);
        if (h == 0) {
            const float* xi = (i < Uc) ? ue + (size_t)uid[i] * Dc
                                       : pe + (size_t)pid[i - Uc] * Dc;
            float2 a2 = *(const float2*)(xi + ln * 2);
            acc.x = di[r] * a2.x;
            acc.y = di[r] * a2.y;
        }
        int j = j0;
        for (; j + 8 <= j1; j += 8) {   // 8 loads in flight
            float2 r0 = *(const float2*)(sptr[r][j] + ln * 2);
            float2 r1 = *(const float2*)(sptr[r][j + 1] + ln * 2);
            float2 r2 = *(const float2*)(sptr[r][j + 2] + ln * 2);
            float2 r3 = *(const float2*)(sptr[r][j + 3] + ln * 2);
            float2 r4 = *(const float2*)(sptr[r][j + 4] + ln * 2);
            float2 r5 = *(const float2*)(sptr[r][j + 5] + ln * 2);
            float2 r6 = *(const float2*)(sptr[r][j + 6] + ln * 2);
            float2 r7 = *(const float2*)(sptr[r][j + 7] + ln * 2);
            float n0 = snrm[r][j],     n1 = snrm[r][j + 1];
            float n2 = snrm[r][j + 2], n3 = snrm[r][j + 3];
            float n4 = snrm[r][j + 4], n5 = snrm[r][j + 5];
            float n6 = snrm[r][j + 6], n7 = snrm[r][j + 7];
            acc.x += (n0 * r0.x + n1 * r1.x) + (n2 * r2.x + n3 * r3.x)
                   + (n4 * r4.x + n5 * r5.x) + (n6 * r6.x + n7 * r7.x);
            acc.y += (n0 * r0.y + n1 * r1.y) + (n2 * r2.y + n3 * r3.y)
                   + (n4 * r4.y + n5 * r5.y) + (n6 * r6.y + n7 * r7.y);
        }
        for (; j < j1; j++) {
            float2 r0 = *(const float2*)(sptr[r][j] + ln * 2);
            acc.x += snrm[r][j] * r0.x;
            acc.y += snrm[r][j] * r0.y;
        }
        pagg[wv][ln * 2]     = acc.x;
        pagg[wv][ln * 2 + 1] = acc.y;
    }
    __syncthreads();
    {   // combine halves: thread -> (node r = t>>7, feature f = t&127)
        int r = t >> 7, f = t & 127;
        agg[r][f] = di[r] * (pagg[2 * r][f] + pagg[2 * r + 1][f]);
    }
    __syncthreads();
    // GEMV: thread = column t
    float a0 = 0.f, a1 = 0.f;
#pragma unroll 4
    for (int k = 0; k < Dc; k += 4) {
        float4 g0 = *(const float4*)&agg[0][k];
        float4 g1 = *(const float4*)&agg[1][k];
        float w0 = W0[(size_t)(k + 0) * Hc + t];
        float w1 = W0[(size_t)(k + 1) * Hc + t];
        float w2 = W0[(size_t)(k + 2) * Hc + t];
        float w3 = W0[(size_t)(k + 3) * Hc + t];
        a0 += g0.x * w0 + g0.y * w1 + g0.z * w2 + g0.w * w3;
        a1 += g1.x * w0 + g1.y * w1 + g1.z * w2 + g1.w * w3;
    }
    float bb = b0[t];
    out[(size_t)(ibase + 0) * Hc + t] = fmaxf(a0 + bb, 0.f);
    out[(size_t)(ibase + 1) * Hc + t] = fmaxf(a1 + bb, 0.f);
}

// Wave-pair H-dim aggregation for 2 nodes: wave wv -> (node wv>>1, half wv&1),
// lane l -> 4 features. 8 row-loads in flight per lane. Partials to pagg.
__device__ __forceinline__ void agg_wave2(const float* __restrict__ X,
                                          const int (*sidx)[CAP], const float (*snrm)[CAP],
                                          const int* c, const float* di, int ibase,
                                          float (*pagg)[Hc], int t) {
    int wv = t >> 6, ln = t & 63;
    int r = wv >> 1, h = wv & 1;
    int dg = min(c[r], CAP);
    int dg2 = dg >> 1;
    int j0 = h ? dg2 : 0, j1 = h ? dg : dg2;
    float4 acc = make_float4(0.f, 0.f, 0.f, 0.f);
    if (h == 0) {
        acc = *(const float4*)&X[(size_t)(ibase + r) * Hc + ln * 4];
        acc.x *= di[r]; acc.y *= di[r]; acc.z *= di[r]; acc.w *= di[r];
    }
    int j = j0;
    for (; j + 8 <= j1; j += 8) {   // 8 loads in flight
        float4 r0 = *(const float4*)&X[sidx[r][j]     + ln * 4];
        float4 r1 = *(const float4*)&X[sidx[r][j + 1] + ln * 4];
        float4 r2 = *(const float4*)&X[sidx[r][j + 2] + ln * 4];
        float4 r3 = *(const float4*)&X[sidx[r][j + 3] + ln * 4];
        float4 r4 = *(const float4*)&X[sidx[r][j + 4] + ln * 4];
        float4 r5 = *(const float4*)&X[sidx[r][j + 5] + ln * 4];
        float4 r6 = *(const float4*)&X[sidx[r][j + 6] + ln * 4];
        float4 r7 = *(const float4*)&X[sidx[r][j + 7] + ln * 4];
        float n0 = snrm[r][j],     n1 = snrm[r][j + 1];
        float n2 = snrm[r][j + 2], n3 = snrm[r][j + 3];
        float n4 = snrm[r][j + 4], n5 = snrm[r][j + 5];
        float n6 = snrm[r][j + 6], n7 = snrm[r][j + 7];
        fma4(acc, n0, r0); fma4(acc, n1, r1); fma4(acc, n2, r2); fma4(acc, n3, r3);
        fma4(acc, n4, r4); fma4(acc, n5, r5); fma4(acc, n6, r6); fma4(acc, n7, r7);
    }
    for (; j < j1; j++) {
        float4 r0 = *(const float4*)&X[sidx[r][j] + ln * 4];
        fma4(acc, snrm[r][j], r0);
    }
    *(float4*)&pagg[wv][ln * 4] = acc;
}

// ---------------- middle layer: agg(X) @ W1 + b1, relu -> out ------------------
// 2 nodes / block, 768 blocks.
__global__ void k_lh(const float* __restrict__ X, const float* __restrict__ W,
                     const float* __restrict__ bias, const int* __restrict__ cnt,
                     const int* __restrict__ colF, float* __restrict__ out) {
    __shared__ int sidx[2][CAP];
    __shared__ float snrm[2][CAP];
    __shared__ __align__(16) float pagg[4][Hc];
    __shared__ __align__(16) float agg[2][Hc];
    int t = threadIdx.x, b = blockIdx.x;
    int ibase = b * 2;
    int c[2]; float di[2];
#pragma unroll
    for (int r = 0; r < 2; r++) {
        c[r] = cnt[ibase + r];
        di[r] = rsqrtf((float)(c[r] + 1));
        int deg = min(c[r], CAP);
        if (t < deg) {
            int s = colF[(ibase + r) * CAP + t];
            sidx[r][t] = s * Hc;
            snrm[r][t] = rsqrtf((float)(cnt[s] + 1));
        }
    }
    __syncthreads();
    agg_wave2(X, sidx, snrm, c, di, ibase, pagg, t);
    __syncthreads();
    agg[0][t] = di[0] * (pagg[0][t] + pagg[1][t]);
    agg[1][t] = di[1] * (pagg[2][t] + pagg[3][t]);
    __syncthreads();
    float a0 = 0.f, a1 = 0.f;
#pragma unroll 4
    for (int k = 0; k < Hc; k += 4) {
        float4 g0 = *(const float4*)&agg[0][k];
        float4 g1 = *(const float4*)&agg[1][k];
        float w0 = W[(size_t)(k + 0) * Hc + t];
        float w1 = W[(size_t)(k + 1) * Hc + t];
        float w2 = W[(size_t)(k + 2) * Hc + t];
        float w3 = W[(size_t)(k + 3) * Hc + t];
        a0 += g0.x * w0 + g0.y * w1 + g0.z * w2 + g0.w * w3;
        a1 += g1.x * w0 + g1.y * w1 + g1.z * w2 + g1.w * w3;
    }
    float bb = bias[t];
    out[(size_t)(ibase + 0) * Hc + t] = fmaxf(a0 + bb, 0.f);
    out[(size_t)(ibase + 1) * Hc + t] = fmaxf(a1 + bb, 0.f);
}

// ---------------- last layer + predictor-operand fusion ------------------------
// 2 nodes / block, 768 blocks (b<256 -> users, else papers).
__global__ void k_lht(const float* __restrict__ X, const float* __restrict__ W2,
                      const float* __restrict__ b2, const int* __restrict__ cnt,
                      const int* __restrict__ colF,
                      const float* __restrict__ Wup, const float* __restrict__ Wpp,
                      const float* __restrict__ bvu, const float* __restrict__ bvp,
                      float* __restrict__ AuT, float* __restrict__ ApT) {
    __shared__ int sidx[2][CAP];
    __shared__ float snrm[2][CAP];
    __shared__ __align__(16) float pagg[4][Hc];
    __shared__ __align__(16) float agg[2][Hc];
    __shared__ __align__(16) float xloc[2][Hc];
    int t = threadIdx.x, b = blockIdx.x;
    int ibase = b * 2;
    int c[2]; float di[2];
#pragma unroll
    for (int r = 0; r < 2; r++) {
        c[r] = cnt[ibase + r];
        di[r] = rsqrtf((float)(c[r] + 1));
        int deg = min(c[r], CAP);
        if (t < deg) {
            int s = colF[(ibase + r) * CAP + t];
            sidx[r][t] = s * Hc;
            snrm[r][t] = rsqrtf((float)(cnt[s] + 1));
        }
    }
    __syncthreads();
    agg_wave2(X, sidx, snrm, c, di, ibase, pagg, t);
    __syncthreads();
    agg[0][t] = di[0] * (pagg[0][t] + pagg[1][t]);
    agg[1][t] = di[1] * (pagg[2][t] + pagg[3][t]);
    __syncthreads();
    // GEMV 1: x = relu(agg @ W2 + b2) -> xloc
    {
        float a0 = 0.f, a1 = 0.f;
#pragma unroll 4
        for (int k = 0; k < Hc; k += 4) {
            float4 g0 = *(const float4*)&agg[0][k];
            float4 g1 = *(const float4*)&agg[1][k];
            float w0 = W2[(size_t)(k + 0) * Hc + t];
            float w1 = W2[(size_t)(k + 1) * Hc + t];
            float w2 = W2[(size_t)(k + 2) * Hc + t];
            float w3 = W2[(size_t)(k + 3) * Hc + t];
            a0 += g0.x * w0 + g0.y * w1 + g0.z * w2 + g0.w * w3;
            a1 += g1.x * w0 + g1.y * w1 + g1.z * w2 + g1.w * w3;
        }
        float bb = b2[t];
        xloc[0][t] = fmaxf(a0 + bb, 0.f);
        xloc[1][t] = fmaxf(a1 + bb, 0.f);
    }
    __syncthreads();
    // GEMV 2: AuT/ApT[t][rloc..rloc+2] = xloc @ Wsel[:,t] + bsel[t]
    {
        const float* Wsel = (b < 256) ? Wup : Wpp;
        const float* bsel = (b < 256) ? bvu : bvp;
        float* YT  = (b < 256) ? AuT : ApT;
        int ldy    = (b < 256) ? Uc : Pc;
        int rloc   = (b < 256) ? ibase : ibase - Uc;
        float a0 = 0.f, a1 = 0.f;
#pragma unroll 4
        for (int k = 0; k < Hc; k += 4) {
            float4 g0 = *(const float4*)&xloc[0][k];
            float4 g1 = *(const float4*)&xloc[1][k];
            float w0 = Wsel[(size_t)(k + 0) * Hc + t];
            float w1 = Wsel[(size_t)(k + 1) * Hc + t];
            float w2 = Wsel[(size_t)(k + 2) * Hc + t];
            float w3 = Wsel[(size_t)(k + 3) * Hc + t];
            a0 += g0.x * w0 + g0.y * w1 + g0.z * w2 + g0.w * w3;
            a1 += g1.x * w0 + g1.y * w1 + g1.z * w2 + g1.w * w3;
        }
        float bb = bsel[t];
        *(float2*)&YT[(size_t)t * ldy + rloc] = make_float2(a0 + bb, a1 + bb);
    }
}

// ---------------- predictor ----------------
__global__ void k_pred(const float* __restrict__ AuT, const float* __restrict__ ApT,
                       const float* __restrict__ Wq2, const float* __restrict__ bq2,
                       float* __restrict__ out) {
    __shared__ float auS[Hc * 16];   // auS[k*16 + u]
    int t = threadIdx.x;
    int ub = blockIdx.x * 16, pb = blockIdx.y * 64;
#pragma unroll
    for (int i = t; i < Hc * 16; i += 256) {
        int k = i >> 4, u = i & 15;
        auS[i] = AuT[(size_t)k * Uc + ub + u];
    }
    __syncthreads();
    int uu = t >> 5;          // 0..7 -> 2 users each
    int pp = t & 31;          // 0..31 -> 2 papers each
    const float* app = ApT + pb + pp * 2;
    const float* aup = auS + uu * 2;
    float acc[2][2] = {};
#pragma unroll 4
    for (int k = 0; k < Hc; k += 4) {
        float4 wv = *(const float4*)&Wq2[k];   // uniform -> s_load
        float2 a[4], p2[4];
#pragma unroll
        for (int j = 0; j < 4; j++) a[j] = *(const float2*)(aup + (k + j) * 16);
#pragma unroll
        for (int j = 0; j < 4; j++) p2[j] = *(const float2*)(app + (size_t)(k + j) * Pc);
        const float* w = (const float*)&wv;
#pragma unroll
        for (int j = 0; j < 4; j++) {
            float a0 = a[j].x, a1 = a[j].y;
            float p0 = p2[j].x, p1 = p2[j].y;
            acc[0][0] += fmaxf(a0 + p0, 0.f) * w[j];
            acc[0][1] += fmaxf(a0 + p1, 0.f) * w[j];
            acc[1][0] += fmaxf(a1 + p0, 0.f) * w[j];
            acc[1][1] += fmaxf(a1 + p1, 0.f) * w[j];
        }
    }
    float bq = bq2[0];
#pragma unroll
    for (int r = 0; r < 2; r++) {
        int u = ub + uu * 2 + r;
        float2 o;
        o.x = 1.f / (1.f + __expf(-(acc[r][0] + bq)));
        o.y = 1.f / (1.f + __expf(-(acc[r][1] + bq)));
        *(float2*)&out[(size_t)u * Pc + pb + pp * 2] = o;
    }
}

// ---------------- launcher ----------------

extern "C" void kernel_launch(void* const* d_in, const int* in_sizes, int n_in,
                              void* d_out, int out_size, void* d_ws, size_t ws_size,
                              hipStream_t stream) {
    const int*   uid = (const int*)d_in[0];
    const int*   pid = (const int*)d_in[1];
    const int*   ei  = (const int*)d_in[2];   // [2,E]: src = ei[0..E), dst = ei[E..2E)
    const float* ue  = (const float*)d_in[4];
    const float* pe  = (const float*)d_in[5];
    const float* W0  = (const float*)d_in[6];  const float* b0 = (const float*)d_in[7];
    const float* W1  = (const float*)d_in[8];  const float* b1 = (const float*)d_in[9];
    const float* W2  = (const float*)d_in[10]; const float* b2 = (const float*)d_in[11];
    const float* Wu  = (const float*)d_in[12]; const float* bu = (const float*)d_in[13];
    const float* Wp  = (const float*)d_in[14]; const float* bp = (const float*)d_in[15];
    const float* Wq1 = (const float*)d_in[16]; const float* bq1 = (const float*)d_in[17];
    const float* Wq2 = (const float*)d_in[18]; const float* bq2 = (const float*)d_in[19];

    const int* e_src = ei;
    const int* e_dst = ei + Ec;

    char* w = (char*)d_ws;
    auto alloc = [&](size_t bytes) { char* p = w; w += (bytes + 255) & ~size_t(255); return p; };
    int*   cnt  = (int*)alloc(Nc * 4);
    int*   colF = (int*)alloc((size_t)Nc * CAP * 4);
    float* xA   = (float*)alloc((size_t)Nc * Hc * 4);
    float* xB   = (float*)alloc((size_t)Nc * Hc * 4);
    float* Wup  = (float*)alloc((size_t)Hc * Hc * 4);
    float* Wpp  = (float*)alloc((size_t)Hc * Hc * 4);
    float* bvu  = (float*)alloc(Hc * 4);
    float* bvp  = (float*)alloc(Hc * 4);
    float* AuT  = (float*)alloc((size_t)Hc * Uc * 4);
    float* ApT  = (float*)alloc((size_t)Hc * Pc * 4);
    float* pred = (float*)d_out;

    // 0: zero bucket counters (tiny DMA)
    hipMemsetAsync(cnt, 0, Nc * 4, stream);
    // 1: scatter | weight collapse | bias collapse
    k_front<<<642, 256, 0, stream>>>(e_src, e_dst, cnt, colF, Wu, Wp, Wq1,
                                     bu, bp, bq1, Wup, Wpp, bvu, bvp);
    // 2-4: fused GCN layers (2 nodes/block, wave-pair neighbor split, 8-deep ILP)
    k_l0<<<Nc / 2, 256, 0, stream>>>(uid, pid, ue, pe, W0, b0, cnt, colF, xA);
    k_lh<<<Nc / 2, 256, 0, stream>>>(xA, W1, b1, cnt, colF, xB);
    k_lht<<<Nc / 2, 256, 0, stream>>>(xB, W2, b2, cnt, colF, Wup, Wpp, bvu, bvp, AuT, ApT);
    // 5: predictor
    k_pred<<<dim3(Uc / 16, Pc / 64), 256, 0, stream>>>(AuT, ApT, Wq2, bq2, pred);
}

// Round 15
// 195.137 us; speedup vs baseline: 1.0638x; 1.0638x over previous
//
#include <hip/hip_runtime.h>
#include <math.h>

// Problem constants
constexpr int Uc = 512;
constexpr int Pc = 1024;
constexpr int Dc = 128;
constexpr int Hc = 256;
constexpr int Ec = 98304;
constexpr int Nc = 1536;   // U + P
constexpr int CAP = 192;   // bucket capacity (deg ~ B(98304,1/1536): mu=64, sigma=8)

__device__ __forceinline__ void fma4(float4& a, float n, const float4 r) {
    a.x += n * r.x; a.y += n * r.y; a.z += n * r.z; a.w += n * r.w;
}

// ---------------- GEMM core: 16 rows x 32 cols / 256-thread block ----------------
template <int K>
__device__ __forceinline__ void gemm_core16(const float* __restrict__ xr,
                                            const float* __restrict__ wc, int M,
                                            float& acc0, float& acc1) {
#pragma unroll 4
    for (int k = 0; k < K; k += 4) {
        float4 a = *(const float4*)(xr + k);
        float2 b0 = *(const float2*)(wc + (size_t)k * M);
        float2 b1 = *(const float2*)(wc + (size_t)(k + 1) * M);
        float2 b2 = *(const float2*)(wc + (size_t)(k + 2) * M);
        float2 b3 = *(const float2*)(wc + (size_t)(k + 3) * M);
        acc0 += a.x * b0.x; acc1 += a.x * b0.y;
        acc0 += a.y * b1.x; acc1 += a.y * b1.y;
        acc0 += a.z * b2.x; acc1 += a.z * b2.y;
        acc0 += a.w * b3.x; acc1 += a.w * b3.y;
    }
}

// ---------------- front kernel: scatter | weight collapse | bias ----------------
__global__ void k_front(const int* __restrict__ e_src, const int* __restrict__ e_dst,
                        int* __restrict__ cnt, int* __restrict__ colF,
                        const float* __restrict__ Wu, const float* __restrict__ Wp,
                        const float* __restrict__ Wq1, const float* __restrict__ bu,
                        const float* __restrict__ bp, const float* __restrict__ bq1,
                        float* __restrict__ Wup, float* __restrict__ Wpp,
                        float* __restrict__ bvu, float* __restrict__ bvp) {
    int t = threadIdx.x, b = blockIdx.x;
    if (b < 384) {
        int e = b * 256 + t;
        int d = e_dst[e];
        int pos = atomicAdd(&cnt[d], 1);
        if (pos < CAP) colF[d * CAP + pos] = e_src[e];
    } else if (b < 640) {
        int id = b - 384;
        int z = id >> 7, tile = id & 127;
        int tx = t & 15, ty = t >> 4;
        const float* X = z ? Wp : Wu;
        const float* W = Wq1 + (z ? (size_t)Dc * Hc : 0);
        float* Y = z ? Wpp : Wup;
        int row = (tile >> 3) * 16 + ty, col = (tile & 7) * 32 + tx * 2;
        float a0 = 0.f, a1 = 0.f;
        gemm_core16<Dc>(X + (size_t)row * Dc, W + col, Hc, a0, a1);
        *(float2*)&Y[(size_t)row * Hc + col] = make_float2(a0, a1);
    } else if (b == 640) {
        float s = bq1[t];
#pragma unroll 8
        for (int d = 0; d < Dc; d++) s += bu[d] * Wq1[d * Hc + t];
        bvu[t] = s;
    } else {
        float s = 0.f;
#pragma unroll 8
        for (int d = 0; d < Dc; d++) s += bp[d] * Wq1[(Dc + d) * Hc + t];
        bvp[t] = s;
    }
}

// ---------------- layer 0: agg(embeddings) @ W0 + b0, relu -> xA ---------------
// 2 nodes / block, 768 blocks. Waves (2r, 2r+1) aggregate node r over neighbor
// halves; lane l -> features 2l..2l+2 (D=128). Partials combined in LDS. [r12]
__global__ void k_l0(const int* __restrict__ uid, const int* __restrict__ pid,
                     const float* __restrict__ ue, const float* __restrict__ pe,
                     const float* __restrict__ W0, const float* __restrict__ b0,
                     const int* __restrict__ cnt, const int* __restrict__ colF,
                     float* __restrict__ out) {
    __shared__ const float* sptr[2][CAP];
    __shared__ float snrm[2][CAP];
    __shared__ __align__(16) float pagg[4][Dc];
    __shared__ __align__(16) float agg[2][Dc];
    int t = threadIdx.x, b = blockIdx.x;
    int ibase = b * 2;
    int c[2]; float di[2];
#pragma unroll
    for (int r = 0; r < 2; r++) {
        c[r] = cnt[ibase + r];
        di[r] = rsqrtf((float)(c[r] + 1));
        int deg = min(c[r], CAP);
        if (t < deg) {
            int s = colF[(ibase + r) * CAP + t];
            sptr[r][t] = (s < Uc) ? ue + (size_t)uid[s] * Dc
                                  : pe + (size_t)pid[s - Uc] * Dc;
            snrm[r][t] = rsqrtf((float)(cnt[s] + 1));
        }
    }
    __syncthreads();
    {   // wave wv: node r = wv>>1, neighbor half h = wv&1
        int wv = t >> 6, ln = t & 63;
        int r = wv >> 1, h = wv & 1;
        int i = ibase + r;
        int dg = min(c[r], CAP);
        int dg2 = dg >> 1;
        int j0 = h ? dg2 : 0, j1 = h ? dg : dg2;
        float2 acc = make_float2(0.f, 0.f);
        if (h == 0) {
            const float* xi = (i < Uc) ? ue + (size_t)uid[i] * Dc
                                       : pe + (size_t)pid[i - Uc] * Dc;
            float2 a2 = *(const float2*)(xi + ln * 2);
            acc.x = di[r] * a2.x;
            acc.y = di[r] * a2.y;
        }
        int j = j0;
        for (; j + 4 <= j1; j += 4) {
            float n0 = snrm[r][j],     n1 = snrm[r][j + 1];
            float n2 = snrm[r][j + 2], n3 = snrm[r][j + 3];
            float2 r0 = *(const float2*)(sptr[r][j] + ln * 2);
            float2 r1 = *(const float2*)(sptr[r][j + 1] + ln * 2);
            float2 r2 = *(const float2*)(sptr[r][j + 2] + ln * 2);
            float2 r3 = *(const float2*)(sptr[r][j + 3] + ln * 2);
            acc.x += n0 * r0.x + n1 * r1.x + n2 * r2.x + n3 * r3.x;
            acc.y += n0 * r0.y + n1 * r1.y + n2 * r2.y + n3 * r3.y;
        }
        for (; j < j1; j++) {
            float2 r0 = *(const float2*)(sptr[r][j] + ln * 2);
            acc.x += snrm[r][j] * r0.x;
            acc.y += snrm[r][j] * r0.y;
        }
        pagg[wv][ln * 2]     = acc.x;
        pagg[wv][ln * 2 + 1] = acc.y;
    }
    __syncthreads();
    {   // combine halves: thread -> (node r = t>>7, feature f = t&127)
        int r = t >> 7, f = t & 127;
        agg[r][f] = di[r] * (pagg[2 * r][f] + pagg[2 * r + 1][f]);
    }
    __syncthreads();
    // GEMV: thread = column t
    float a0 = 0.f, a1 = 0.f;
#pragma unroll 2
    for (int k = 0; k < Dc; k += 4) {
        float4 g0 = *(const float4*)&agg[0][k];
        float4 g1 = *(const float4*)&agg[1][k];
        float w0 = W0[(size_t)(k + 0) * Hc + t];
        float w1 = W0[(size_t)(k + 1) * Hc + t];
        float w2 = W0[(size_t)(k + 2) * Hc + t];
        float w3 = W0[(size_t)(k + 3) * Hc + t];
        a0 += g0.x * w0 + g0.y * w1 + g0.z * w2 + g0.w * w3;
        a1 += g1.x * w0 + g1.y * w1 + g1.z * w2 + g1.w * w3;
    }
    float bb = b0[t];
    out[(size_t)(ibase + 0) * Hc + t] = fmaxf(a0 + bb, 0.f);
    out[(size_t)(ibase + 1) * Hc + t] = fmaxf(a1 + bb, 0.f);
}

// Wave-pair H-dim aggregation for 2 nodes: wave wv -> (node wv>>1, half wv&1),
// lane l -> 4 features. Partials to pagg; caller combines. [r12 4-deep]
__device__ __forceinline__ void agg_wave2(const float* __restrict__ X,
                                          const int (*sidx)[CAP], const float (*snrm)[CAP],
                                          const int* c, const float* di, int ibase,
                                          float (*pagg)[Hc], int t) {
    int wv = t >> 6, ln = t & 63;
    int r = wv >> 1, h = wv & 1;
    int dg = min(c[r], CAP);
    int dg2 = dg >> 1;
    int j0 = h ? dg2 : 0, j1 = h ? dg : dg2;
    float4 acc = make_float4(0.f, 0.f, 0.f, 0.f);
    if (h == 0) {
        acc = *(const float4*)&X[(size_t)(ibase + r) * Hc + ln * 4];
        acc.x *= di[r]; acc.y *= di[r]; acc.z *= di[r]; acc.w *= di[r];
    }
    int j = j0;
    for (; j + 4 <= j1; j += 4) {
        float n0 = snrm[r][j],     n1 = snrm[r][j + 1];
        float n2 = snrm[r][j + 2], n3 = snrm[r][j + 3];
        float4 r0 = *(const float4*)&X[sidx[r][j]     + ln * 4];
        float4 r1 = *(const float4*)&X[sidx[r][j + 1] + ln * 4];
        float4 r2 = *(const float4*)&X[sidx[r][j + 2] + ln * 4];
        float4 r3 = *(const float4*)&X[sidx[r][j + 3] + ln * 4];
        fma4(acc, n0, r0); fma4(acc, n1, r1); fma4(acc, n2, r2); fma4(acc, n3, r3);
    }
    for (; j < j1; j++) {
        float4 r0 = *(const float4*)&X[sidx[r][j] + ln * 4];
        fma4(acc, snrm[r][j], r0);
    }
    *(float4*)&pagg[wv][ln * 4] = acc;
}

// ---------------- middle layer: agg(X) @ W1 + b1, relu -> out ------------------
// 2 nodes / block, 768 blocks. [r12]
__global__ void k_lh(const float* __restrict__ X, const float* __restrict__ W,
                     const float* __restrict__ bias, const int* __restrict__ cnt,
                     const int* __restrict__ colF, float* __restrict__ out) {
    __shared__ int sidx[2][CAP];
    __shared__ float snrm[2][CAP];
    __shared__ __align__(16) float pagg[4][Hc];
    __shared__ __align__(16) float agg[2][Hc];
    int t = threadIdx.x, b = blockIdx.x;
    int ibase = b * 2;
    int c[2]; float di[2];
#pragma unroll
    for (int r = 0; r < 2; r++) {
        c[r] = cnt[ibase + r];
        di[r] = rsqrtf((float)(c[r] + 1));
        int deg = min(c[r], CAP);
        if (t < deg) {
            int s = colF[(ibase + r) * CAP + t];
            sidx[r][t] = s * Hc;
            snrm[r][t] = rsqrtf((float)(cnt[s] + 1));
        }
    }
    __syncthreads();
    agg_wave2(X, sidx, snrm, c, di, ibase, pagg, t);
    __syncthreads();
    agg[0][t] = di[0] * (pagg[0][t] + pagg[1][t]);
    agg[1][t] = di[1] * (pagg[2][t] + pagg[3][t]);
    __syncthreads();
    float a0 = 0.f, a1 = 0.f;
#pragma unroll 2
    for (int k = 0; k < Hc; k += 4) {
        float4 g0 = *(const float4*)&agg[0][k];
        float4 g1 = *(const float4*)&agg[1][k];
        float w0 = W[(size_t)(k + 0) * Hc + t];
        float w1 = W[(size_t)(k + 1) * Hc + t];
        float w2 = W[(size_t)(k + 2) * Hc + t];
        float w3 = W[(size_t)(k + 3) * Hc + t];
        a0 += g0.x * w0 + g0.y * w1 + g0.z * w2 + g0.w * w3;
        a1 += g1.x * w0 + g1.y * w1 + g1.z * w2 + g1.w * w3;
    }
    float bb = bias[t];
    out[(size_t)(ibase + 0) * Hc + t] = fmaxf(a0 + bb, 0.f);
    out[(size_t)(ibase + 1) * Hc + t] = fmaxf(a1 + bb, 0.f);
}

// ---------------- last layer + predictor-operand fusion ------------------------
// 4 nodes / block, 384 blocks (b<128 -> users, else papers). Wave-per-node
// aggregation; both GEMVs amortize each W element over 4 FMAs (halved W L2
// traffic vs 2-node); float4 transposed store (full 16B lines).
__global__ void k_lht(const float* __restrict__ X, const float* __restrict__ W2,
                      const float* __restrict__ b2, const int* __restrict__ cnt,
                      const int* __restrict__ colF,
                      const float* __restrict__ Wup, const float* __restrict__ Wpp,
                      const float* __restrict__ bvu, const float* __restrict__ bvp,
                      float* __restrict__ AuT, float* __restrict__ ApT) {
    __shared__ int sidx[4][CAP];
    __shared__ float snrm[4][CAP];
    __shared__ __align__(16) float agg[4][Hc];
    __shared__ __align__(16) float xloc[4][Hc];
    int t = threadIdx.x, b = blockIdx.x;
    int ibase = b * 4;
    int c[4]; float di[4];
#pragma unroll
    for (int r = 0; r < 4; r++) {
        c[r] = cnt[ibase + r];
        di[r] = rsqrtf((float)(c[r] + 1));
        int deg = min(c[r], CAP);
        if (t < deg) {
            int s = colF[(ibase + r) * CAP + t];
            sidx[r][t] = s * Hc;
            snrm[r][t] = rsqrtf((float)(cnt[s] + 1));
        }
    }
    __syncthreads();
    {   // wave wv -> node wv, full neighbor list; lane l -> 4 features
        int wv = t >> 6, ln = t & 63;
        int dg = min(c[wv], CAP);
        float4 acc = *(const float4*)&X[(size_t)(ibase + wv) * Hc + ln * 4];
        acc.x *= di[wv]; acc.y *= di[wv]; acc.z *= di[wv]; acc.w *= di[wv];
        int j = 0;
        for (; j + 4 <= dg; j += 4) {
            float n0 = snrm[wv][j],     n1 = snrm[wv][j + 1];
            float n2 = snrm[wv][j + 2], n3 = snrm[wv][j + 3];
            float4 r0 = *(const float4*)&X[sidx[wv][j]     + ln * 4];
            float4 r1 = *(const float4*)&X[sidx[wv][j + 1] + ln * 4];
            float4 r2 = *(const float4*)&X[sidx[wv][j + 2] + ln * 4];
            float4 r3 = *(const float4*)&X[sidx[wv][j + 3] + ln * 4];
            fma4(acc, n0, r0); fma4(acc, n1, r1); fma4(acc, n2, r2); fma4(acc, n3, r3);
        }
        for (; j < dg; j++) {
            float4 r0 = *(const float4*)&X[sidx[wv][j] + ln * 4];
            fma4(acc, snrm[wv][j], r0);
        }
        acc.x *= di[wv]; acc.y *= di[wv]; acc.z *= di[wv]; acc.w *= di[wv];
        *(float4*)&agg[wv][ln * 4] = acc;
    }
    __syncthreads();
    // GEMV 1: x = relu(agg @ W2 + b2) -> xloc (4 FMAs per W element)
    {
        float a0 = 0.f, a1 = 0.f, a2 = 0.f, a3 = 0.f;
#pragma unroll 2
        for (int k = 0; k < Hc; k += 4) {
            float4 g0 = *(const float4*)&agg[0][k];
            float4 g1 = *(const float4*)&agg[1][k];
            float4 g2 = *(const float4*)&agg[2][k];
            float4 g3 = *(const float4*)&agg[3][k];
            float w0 = W2[(size_t)(k + 0) * Hc + t];
            float w1 = W2[(size_t)(k + 1) * Hc + t];
            float w2 = W2[(size_t)(k + 2) * Hc + t];
            float w3 = W2[(size_t)(k + 3) * Hc + t];
            a0 += g0.x * w0 + g0.y * w1 + g0.z * w2 + g0.w * w3;
            a1 += g1.x * w0 + g1.y * w1 + g1.z * w2 + g1.w * w3;
            a2 += g2.x * w0 + g2.y * w1 + g2.z * w2 + g2.w * w3;
            a3 += g3.x * w0 + g3.y * w1 + g3.z * w2 + g3.w * w3;
        }
        float bb = b2[t];
        xloc[0][t] = fmaxf(a0 + bb, 0.f);
        xloc[1][t] = fmaxf(a1 + bb, 0.f);
        xloc[2][t] = fmaxf(a2 + bb, 0.f);
        xloc[3][t] = fmaxf(a3 + bb, 0.f);
    }
    __syncthreads();
    // GEMV 2: AuT/ApT[t][rloc..rloc+4] = xloc @ Wsel[:,t] + bsel[t], float4 store
    {
        const float* Wsel = (b < 128) ? Wup : Wpp;
        const float* bsel = (b < 128) ? bvu : bvp;
        float* YT  = (b < 128) ? AuT : ApT;
        int ldy    = (b < 128) ? Uc : Pc;
        int rloc   = (b < 128) ? ibase : ibase - Uc;
        float a0 = 0.f, a1 = 0.f, a2 = 0.f, a3 = 0.f;
#pragma unroll 2
        for (int k = 0; k < Hc; k += 4) {
            float4 g0 = *(const float4*)&xloc[0][k];
            float4 g1 = *(const float4*)&xloc[1][k];
            float4 g2 = *(const float4*)&xloc[2][k];
            float4 g3 = *(const float4*)&xloc[3][k];
            float w0 = Wsel[(size_t)(k + 0) * Hc + t];
            float w1 = Wsel[(size_t)(k + 1) * Hc + t];
            float w2 = Wsel[(size_t)(k + 2) * Hc + t];
            float w3 = Wsel[(size_t)(k + 3) * Hc + t];
            a0 += g0.x * w0 + g0.y * w1 + g0.z * w2 + g0.w * w3;
            a1 += g1.x * w0 + g1.y * w1 + g1.z * w2 + g1.w * w3;
            a2 += g2.x * w0 + g2.y * w1 + g2.z * w2 + g2.w * w3;
            a3 += g3.x * w0 + g3.y * w1 + g3.z * w2 + g3.w * w3;
        }
        float bb = bsel[t];
        float4 o = make_float4(a0 + bb, a1 + bb, a2 + bb, a3 + bb);
        *(float4*)&YT[(size_t)t * ldy + rloc] = o;
    }
}

// ---------------- predictor ----------------
__global__ void k_pred(const float* __restrict__ AuT, const float* __restrict__ ApT,
                       const float* __restrict__ Wq2, const float* __restrict__ bq2,
                       float* __restrict__ out) {
    __shared__ float auS[Hc * 16];   // auS[k*16 + u]
    int t = threadIdx.x;
    int ub = blockIdx.x * 16, pb = blockIdx.y * 64;
#pragma unroll
    for (int i = t; i < Hc * 16; i += 256) {
        int k = i >> 4, u = i & 15;
        auS[i] = AuT[(size_t)k * Uc + ub + u];
    }
    __syncthreads();
    int uu = t >> 5;          // 0..7 -> 2 users each
    int pp = t & 31;          // 0..31 -> 2 papers each
    const float* app = ApT + pb + pp * 2;
    const float* aup = auS + uu * 2;
    float acc[2][2] = {};
#pragma unroll 4
    for (int k = 0; k < Hc; k += 4) {
        float4 wv = *(const float4*)&Wq2[k];   // uniform -> s_load
        float2 a[4], p2[4];
#pragma unroll
        for (int j = 0; j < 4; j++) a[j] = *(const float2*)(aup + (k + j) * 16);
#pragma unroll
        for (int j = 0; j < 4; j++) p2[j] = *(const float2*)(app + (size_t)(k + j) * Pc);
        const float* w = (const float*)&wv;
#pragma unroll
        for (int j = 0; j < 4; j++) {
            float a0 = a[j].x, a1 = a[j].y;
            float p0 = p2[j].x, p1 = p2[j].y;
            acc[0][0] += fmaxf(a0 + p0, 0.f) * w[j];
            acc[0][1] += fmaxf(a0 + p1, 0.f) * w[j];
            acc[1][0] += fmaxf(a1 + p0, 0.f) * w[j];
            acc[1][1] += fmaxf(a1 + p1, 0.f) * w[j];
        }
    }
    float bq = bq2[0];
#pragma unroll
    for (int r = 0; r < 2; r++) {
        int u = ub + uu * 2 + r;
        float2 o;
        o.x = 1.f / (1.f + __expf(-(acc[r][0] + bq)));
        o.y = 1.f / (1.f + __expf(-(acc[r][1] + bq)));
        *(float2*)&out[(size_t)u * Pc + pb + pp * 2] = o;
    }
}

// ---------------- launcher ----------------

extern "C" void kernel_launch(void* const* d_in, const int* in_sizes, int n_in,
                              void* d_out, int out_size, void* d_ws, size_t ws_size,
                              hipStream_t stream) {
    const int*   uid = (const int*)d_in[0];
    const int*   pid = (const int*)d_in[1];
    const int*   ei  = (const int*)d_in[2];   // [2,E]: src = ei[0..E), dst = ei[E..2E)
    const float* ue  = (const float*)d_in[4];
    const float* pe  = (const float*)d_in[5];
    const float* W0  = (const float*)d_in[6];  const float* b0 = (const float*)d_in[7];
    const float* W1  = (const float*)d_in[8];  const float* b1 = (const float*)d_in[9];
    const float* W2  = (const float*)d_in[10]; const float* b2 = (const float*)d_in[11];
    const float* Wu  = (const float*)d_in[12]; const float* bu = (const float*)d_in[13];
    const float* Wp  = (const float*)d_in[14]; const float* bp = (const float*)d_in[15];
    const float* Wq1 = (const float*)d_in[16]; const float* bq1 = (const float*)d_in[17];
    const float* Wq2 = (const float*)d_in[18]; const float* bq2 = (const float*)d_in[19];

    const int* e_src = ei;
    const int* e_dst = ei + Ec;

    char* w = (char*)d_ws;
    auto alloc = [&](size_t bytes) { char* p = w; w += (bytes + 255) & ~size_t(255); return p; };
    int*   cnt  = (int*)alloc(Nc * 4);
    int*   colF = (int*)alloc((size_t)Nc * CAP * 4);
    float* xA   = (float*)alloc((size_t)Nc * Hc * 4);
    float* xB   = (float*)alloc((size_t)Nc * Hc * 4);
    float* Wup  = (float*)alloc((size_t)Hc * Hc * 4);
    float* Wpp  = (float*)alloc((size_t)Hc * Hc * 4);
    float* bvu  = (float*)alloc(Hc * 4);
    float* bvp  = (float*)alloc(Hc * 4);
    float* AuT  = (float*)alloc((size_t)Hc * Uc * 4);
    float* ApT  = (float*)alloc((size_t)Hc * Pc * 4);
    float* pred = (float*)d_out;

    // 0: zero bucket counters (tiny DMA)
    hipMemsetAsync(cnt, 0, Nc * 4, stream);
    // 1: scatter | weight collapse | bias collapse
    k_front<<<642, 256, 0, stream>>>(e_src, e_dst, cnt, colF, Wu, Wp, Wq1,
                                     bu, bp, bq1, Wup, Wpp, bvu, bvp);
    // 2-4: fused GCN layers (l0/lh: r12 2-node wave-pair; lht: 4-node W-amortized)
    k_l0<<<Nc / 2, 256, 0, stream>>>(uid, pid, ue, pe, W0, b0, cnt, colF, xA);
    k_lh<<<Nc / 2, 256, 0, stream>>>(xA, W1, b1, cnt, colF, xB);
    k_lht<<<Nc / 4, 256, 0, stream>>>(xB, W2, b2, cnt, colF, Wup, Wpp, bvu, bvp, AuT, ApT);
    // 5: predictor
    k_pred<<<dim3(Uc / 16, Pc / 64), 256, 0, stream>>>(AuT, ApT, Wq2, bq2, pred);
}

// Round 16
// 193.720 us; speedup vs baseline: 1.0716x; 1.0073x over previous
//
#include <hip/hip_runtime.h>
#include <math.h>

// Problem constants
constexpr int Uc = 512;
constexpr int Pc = 1024;
constexpr int Dc = 128;
constexpr int Hc = 256;
constexpr int Ec = 98304;
constexpr int Nc = 1536;   // U + P
constexpr int CAP = 192;   // bucket capacity (deg ~ B(98304,1/1536): mu=64, sigma=8)

__device__ __forceinline__ void fma4(float4& a, float n, const float4 r) {
    a.x += n * r.x; a.y += n * r.y; a.z += n * r.z; a.w += n * r.w;
}

// ---------------- GEMM core: 16 rows x 32 cols / 256-thread block ----------------
template <int K>
__device__ __forceinline__ void gemm_core16(const float* __restrict__ xr,
                                            const float* __restrict__ wc, int M,
                                            float& acc0, float& acc1) {
#pragma unroll 4
    for (int k = 0; k < K; k += 4) {
        float4 a = *(const float4*)(xr + k);
        float2 b0 = *(const float2*)(wc + (size_t)k * M);
        float2 b1 = *(const float2*)(wc + (size_t)(k + 1) * M);
        float2 b2 = *(const float2*)(wc + (size_t)(k + 2) * M);
        float2 b3 = *(const float2*)(wc + (size_t)(k + 3) * M);
        acc0 += a.x * b0.x; acc1 += a.x * b0.y;
        acc0 += a.y * b1.x; acc1 += a.y * b1.y;
        acc0 += a.z * b2.x; acc1 += a.z * b2.y;
        acc0 += a.w * b3.x; acc1 += a.w * b3.y;
    }
}

// ---------------- front kernel: scatter | weight collapse | bias ----------------
__global__ void k_front(const int* __restrict__ e_src, const int* __restrict__ e_dst,
                        int* __restrict__ cnt, unsigned short* __restrict__ colF,
                        const float* __restrict__ Wu, const float* __restrict__ Wp,
                        const float* __restrict__ Wq1, const float* __restrict__ bu,
                        const float* __restrict__ bp, const float* __restrict__ bq1,
                        float* __restrict__ Wup, float* __restrict__ Wpp,
                        float* __restrict__ bvu, float* __restrict__ bvp) {
    int t = threadIdx.x, b = blockIdx.x;
    if (b < 384) {
        int e = b * 256 + t;
        int d = e_dst[e];
        int pos = atomicAdd(&cnt[d], 1);
        if (pos < CAP) colF[d * CAP + pos] = (unsigned short)e_src[e];
    } else if (b < 640) {
        int id = b - 384;
        int z = id >> 7, tile = id & 127;
        int tx = t & 15, ty = t >> 4;
        const float* X = z ? Wp : Wu;
        const float* W = Wq1 + (z ? (size_t)Dc * Hc : 0);
        float* Y = z ? Wpp : Wup;
        int row = (tile >> 3) * 16 + ty, col = (tile & 7) * 32 + tx * 2;
        float a0 = 0.f, a1 = 0.f;
        gemm_core16<Dc>(X + (size_t)row * Dc, W + col, Hc, a0, a1);
        *(float2*)&Y[(size_t)row * Hc + col] = make_float2(a0, a1);
    } else if (b == 640) {
        float s = bq1[t];
#pragma unroll 8
        for (int d = 0; d < Dc; d++) s += bu[d] * Wq1[d * Hc + t];
        bvu[t] = s;
    } else {
        float s = 0.f;
#pragma unroll 8
        for (int d = 0; d < Dc; d++) s += bp[d] * Wq1[(Dc + d) * Hc + t];
        bvp[t] = s;
    }
}

// ---------------- layer 0: agg(embeddings) @ W0 + b0, relu -> xA ---------------
// 2 nodes / block, 768 blocks. Waves (2r, 2r+1) aggregate node r over neighbor
// halves; lane l -> features 2l..2l+2 (D=128). Partials combined in LDS. [r12]
__global__ void k_l0(const int* __restrict__ uid, const int* __restrict__ pid,
                     const float* __restrict__ ue, const float* __restrict__ pe,
                     const float* __restrict__ W0, const float* __restrict__ b0,
                     const int* __restrict__ cnt, const unsigned short* __restrict__ colF,
                     float* __restrict__ out) {
    __shared__ const float* sptr[2][CAP];
    __shared__ float snrm[2][CAP];
    __shared__ __align__(16) float pagg[4][Dc];
    __shared__ __align__(16) float agg[2][Dc];
    int t = threadIdx.x, b = blockIdx.x;
    int ibase = b * 2;
    int c[2]; float di[2];
#pragma unroll
    for (int r = 0; r < 2; r++) {
        c[r] = cnt[ibase + r];
        di[r] = rsqrtf((float)(c[r] + 1));
        int deg = min(c[r], CAP);
        if (t < deg) {
            int s = colF[(ibase + r) * CAP + t];
            sptr[r][t] = (s < Uc) ? ue + (size_t)uid[s] * Dc
                                  : pe + (size_t)pid[s - Uc] * Dc;
            snrm[r][t] = rsqrtf((float)(cnt[s] + 1));
        }
    }
    __syncthreads();
    {   // wave wv: node r = wv>>1, neighbor half h = wv&1
        int wv = t >> 6, ln = t & 63;
        int r = wv >> 1, h = wv & 1;
        int i = ibase + r;
        int dg = min(c[r], CAP);
        int dg2 = dg >> 1;
        int j0 = h ? dg2 : 0, j1 = h ? dg : dg2;
        float2 acc = make_float2(0.f, 0.f);
        if (h == 0) {
            const float* xi = (i < Uc) ? ue + (size_t)uid[i] * Dc
                                       : pe + (size_t)pid[i - Uc] * Dc;
            float2 a2 = *(const float2*)(xi + ln * 2);
            acc.x = di[r] * a2.x;
            acc.y = di[r] * a2.y;
        }
        int j = j0;
        for (; j + 4 <= j1; j += 4) {
            float n0 = snrm[r][j],     n1 = snrm[r][j + 1];
            float n2 = snrm[r][j + 2], n3 = snrm[r][j + 3];
            float2 r0 = *(const float2*)(sptr[r][j] + ln * 2);
            float2 r1 = *(const float2*)(sptr[r][j + 1] + ln * 2);
            float2 r2 = *(const float2*)(sptr[r][j + 2] + ln * 2);
            float2 r3 = *(const float2*)(sptr[r][j + 3] + ln * 2);
            acc.x += n0 * r0.x + n1 * r1.x + n2 * r2.x + n3 * r3.x;
            acc.y += n0 * r0.y + n1 * r1.y + n2 * r2.y + n3 * r3.y;
        }
        for (; j < j1; j++) {
            float2 r0 = *(const float2*)(sptr[r][j] + ln * 2);
            acc.x += snrm[r][j] * r0.x;
            acc.y += snrm[r][j] * r0.y;
        }
        pagg[wv][ln * 2]     = acc.x;
        pagg[wv][ln * 2 + 1] = acc.y;
    }
    __syncthreads();
    {   // combine halves: thread -> (node r = t>>7, feature f = t&127)
        int r = t >> 7, f = t & 127;
        agg[r][f] = di[r] * (pagg[2 * r][f] + pagg[2 * r + 1][f]);
    }
    __syncthreads();
    // GEMV: thread = column t
    float a0 = 0.f, a1 = 0.f;
#pragma unroll 2
    for (int k = 0; k < Dc; k += 4) {
        float4 g0 = *(const float4*)&agg[0][k];
        float4 g1 = *(const float4*)&agg[1][k];
        float w0 = W0[(size_t)(k + 0) * Hc + t];
        float w1 = W0[(size_t)(k + 1) * Hc + t];
        float w2 = W0[(size_t)(k + 2) * Hc + t];
        float w3 = W0[(size_t)(k + 3) * Hc + t];
        a0 += g0.x * w0 + g0.y * w1 + g0.z * w2 + g0.w * w3;
        a1 += g1.x * w0 + g1.y * w1 + g1.z * w2 + g1.w * w3;
    }
    float bb = b0[t];
    out[(size_t)(ibase + 0) * Hc + t] = fmaxf(a0 + bb, 0.f);
    out[(size_t)(ibase + 1) * Hc + t] = fmaxf(a1 + bb, 0.f);
}

// Wave-pair H-dim aggregation for 2 nodes: wave wv -> (node wv>>1, half wv&1),
// lane l -> 4 features. Partials to pagg; caller combines. [r12 4-deep]
__device__ __forceinline__ void agg_wave2(const float* __restrict__ X,
                                          const int (*sidx)[CAP], const float (*snrm)[CAP],
                                          const int* c, const float* di, int ibase,
                                          float (*pagg)[Hc], int t) {
    int wv = t >> 6, ln = t & 63;
    int r = wv >> 1, h = wv & 1;
    int dg = min(c[r], CAP);
    int dg2 = dg >> 1;
    int j0 = h ? dg2 : 0, j1 = h ? dg : dg2;
    float4 acc = make_float4(0.f, 0.f, 0.f, 0.f);
    if (h == 0) {
        acc = *(const float4*)&X[(size_t)(ibase + r) * Hc + ln * 4];
        acc.x *= di[r]; acc.y *= di[r]; acc.z *= di[r]; acc.w *= di[r];
    }
    int j = j0;
    for (; j + 4 <= j1; j += 4) {
        float n0 = snrm[r][j],     n1 = snrm[r][j + 1];
        float n2 = snrm[r][j + 2], n3 = snrm[r][j + 3];
        float4 r0 = *(const float4*)&X[sidx[r][j]     + ln * 4];
        float4 r1 = *(const float4*)&X[sidx[r][j + 1] + ln * 4];
        float4 r2 = *(const float4*)&X[sidx[r][j + 2] + ln * 4];
        float4 r3 = *(const float4*)&X[sidx[r][j + 3] + ln * 4];
        fma4(acc, n0, r0); fma4(acc, n1, r1); fma4(acc, n2, r2); fma4(acc, n3, r3);
    }
    for (; j < j1; j++) {
        float4 r0 = *(const float4*)&X[sidx[r][j] + ln * 4];
        fma4(acc, snrm[r][j], r0);
    }
    *(float4*)&pagg[wv][ln * 4] = acc;
}

// Staging for H-layers: 2 nodes, 256 threads.
__device__ __forceinline__ void stageH(const int* __restrict__ cnt,
                                       const unsigned short* __restrict__ colF,
                                       int ibase, const int* c, int (*sidx)[CAP],
                                       float (*snrm)[CAP], int t) {
#pragma unroll
    for (int r = 0; r < 2; r++) {
        int deg = min(c[r], CAP);
        if (t < deg) {
            int s = colF[(ibase + r) * CAP + t];
            sidx[r][t] = s * Hc;
            snrm[r][t] = rsqrtf((float)(cnt[s] + 1));
        }
    }
}

// ---------------- middle layer: agg(X) @ W1 + b1, relu -> out ------------------
// 2 nodes / block, 768 blocks. [r12]
__global__ void k_lh(const float* __restrict__ X, const float* __restrict__ W,
                     const float* __restrict__ bias, const int* __restrict__ cnt,
                     const unsigned short* __restrict__ colF, float* __restrict__ out) {
    __shared__ int sidx[2][CAP];
    __shared__ float snrm[2][CAP];
    __shared__ __align__(16) float pagg[4][Hc];
    __shared__ __align__(16) float agg[2][Hc];
    int t = threadIdx.x, b = blockIdx.x;
    int ibase = b * 2;
    int c[2]; float di[2];
#pragma unroll
    for (int r = 0; r < 2; r++) {
        c[r] = cnt[ibase + r];
        di[r] = rsqrtf((float)(c[r] + 1));
    }
    stageH(cnt, colF, ibase, c, sidx, snrm, t);
    __syncthreads();
    agg_wave2(X, sidx, snrm, c, di, ibase, pagg, t);
    __syncthreads();
    agg[0][t] = di[0] * (pagg[0][t] + pagg[1][t]);
    agg[1][t] = di[1] * (pagg[2][t] + pagg[3][t]);
    __syncthreads();
    float a0 = 0.f, a1 = 0.f;
#pragma unroll 2
    for (int k = 0; k < Hc; k += 4) {
        float4 g0 = *(const float4*)&agg[0][k];
        float4 g1 = *(const float4*)&agg[1][k];
        float w0 = W[(size_t)(k + 0) * Hc + t];
        float w1 = W[(size_t)(k + 1) * Hc + t];
        float w2 = W[(size_t)(k + 2) * Hc + t];
        float w3 = W[(size_t)(k + 3) * Hc + t];
        a0 += g0.x * w0 + g0.y * w1 + g0.z * w2 + g0.w * w3;
        a1 += g1.x * w0 + g1.y * w1 + g1.z * w2 + g1.w * w3;
    }
    float bb = bias[t];
    out[(size_t)(ibase + 0) * Hc + t] = fmaxf(a0 + bb, 0.f);
    out[(size_t)(ibase + 1) * Hc + t] = fmaxf(a1 + bb, 0.f);
}

// ---------------- last layer + predictor-operand fusion ------------------------
// 2 nodes / block, 768 blocks (b<256 -> users, else papers). [r12]
__global__ void k_lht(const float* __restrict__ X, const float* __restrict__ W2,
                      const float* __restrict__ b2, const int* __restrict__ cnt,
                      const unsigned short* __restrict__ colF,
                      const float* __restrict__ Wup, const float* __restrict__ Wpp,
                      const float* __restrict__ bvu, const float* __restrict__ bvp,
                      float* __restrict__ AuT, float* __restrict__ ApT) {
    __shared__ int sidx[2][CAP];
    __shared__ float snrm[2][CAP];
    __shared__ __align__(16) float pagg[4][Hc];
    __shared__ __align__(16) float agg[2][Hc];
    __shared__ __align__(16) float xloc[2][Hc];
    int t = threadIdx.x, b = blockIdx.x;
    int ibase = b * 2;
    int c[2]; float di[2];
#pragma unroll
    for (int r = 0; r < 2; r++) {
        c[r] = cnt[ibase + r];
        di[r] = rsqrtf((float)(c[r] + 1));
    }
    stageH(cnt, colF, ibase, c, sidx, snrm, t);
    __syncthreads();
    agg_wave2(X, sidx, snrm, c, di, ibase, pagg, t);
    __syncthreads();
    agg[0][t] = di[0] * (pagg[0][t] + pagg[1][t]);
    agg[1][t] = di[1] * (pagg[2][t] + pagg[3][t]);
    __syncthreads();
    // GEMV 1: x = relu(agg @ W2 + b2) -> xloc
    {
        float a0 = 0.f, a1 = 0.f;
#pragma unroll 2
        for (int k = 0; k < Hc; k += 4) {
            float4 g0 = *(const float4*)&agg[0][k];
            float4 g1 = *(const float4*)&agg[1][k];
            float w0 = W2[(size_t)(k + 0) * Hc + t];
            float w1 = W2[(size_t)(k + 1) * Hc + t];
            float w2 = W2[(size_t)(k + 2) * Hc + t];
            float w3 = W2[(size_t)(k + 3) * Hc + t];
            a0 += g0.x * w0 + g0.y * w1 + g0.z * w2 + g0.w * w3;
            a1 += g1.x * w0 + g1.y * w1 + g1.z * w2 + g1.w * w3;
        }
        float bb = b2[t];
        xloc[0][t] = fmaxf(a0 + bb, 0.f);
        xloc[1][t] = fmaxf(a1 + bb, 0.f);
    }
    __syncthreads();
    // GEMV 2: AuT/ApT[t][rloc..rloc+2] = xloc @ Wsel[:,t] + bsel[t]
    {
        const float* Wsel = (b < 256) ? Wup : Wpp;
        const float* bsel = (b < 256) ? bvu : bvp;
        float* YT  = (b < 256) ? AuT : ApT;
        int ldy    = (b < 256) ? Uc : Pc;
        int rloc   = (b < 256) ? ibase : ibase - Uc;
        float a0 = 0.f, a1 = 0.f;
#pragma unroll 2
        for (int k = 0; k < Hc; k += 4) {
            float4 g0 = *(const float4*)&xloc[0][k];
            float4 g1 = *(const float4*)&xloc[1][k];
            float w0 = Wsel[(size_t)(k + 0) * Hc + t];
            float w1 = Wsel[(size_t)(k + 1) * Hc + t];
            float w2 = Wsel[(size_t)(k + 2) * Hc + t];
            float w3 = Wsel[(size_t)(k + 3) * Hc + t];
            a0 += g0.x * w0 + g0.y * w1 + g0.z * w2 + g0.w * w3;
            a1 += g1.x * w0 + g1.y * w1 + g1.z * w2 + g1.w * w3;
        }
        float bb = bsel[t];
        *(float2*)&YT[(size_t)t * ldy + rloc] = make_float2(a0 + bb, a1 + bb);
    }
}

// ---------------- predictor ----------------
__global__ void k_pred(const float* __restrict__ AuT, const float* __restrict__ ApT,
                       const float* __restrict__ Wq2, const float* __restrict__ bq2,
                       float* __restrict__ out) {
    __shared__ float auS[Hc * 16];   // auS[k*16 + u]
    int t = threadIdx.x;
    int ub = blockIdx.x * 16, pb = blockIdx.y * 64;
#pragma unroll
    for (int i = t; i < Hc * 16; i += 256) {
        int k = i >> 4, u = i & 15;
        auS[i] = AuT[(size_t)k * Uc + ub + u];
    }
    __syncthreads();
    int uu = t >> 5;          // 0..7 -> 2 users each
    int pp = t & 31;          // 0..31 -> 2 papers each
    const float* app = ApT + pb + pp * 2;
    const float* aup = auS + uu * 2;
    float acc[2][2] = {};
#pragma unroll 4
    for (int k = 0; k < Hc; k += 4) {
        float4 wv = *(const float4*)&Wq2[k];   // uniform -> s_load
        float2 a[4], p2[4];
#pragma unroll
        for (int j = 0; j < 4; j++) a[j] = *(const float2*)(aup + (k + j) * 16);
#pragma unroll
        for (int j = 0; j < 4; j++) p2[j] = *(const float2*)(app + (size_t)(k + j) * Pc);
        const float* w = (const float*)&wv;
#pragma unroll
        for (int j = 0; j < 4; j++) {
            float a0 = a[j].x, a1 = a[j].y;
            float p0 = p2[j].x, p1 = p2[j].y;
            acc[0][0] += fmaxf(a0 + p0, 0.f) * w[j];
            acc[0][1] += fmaxf(a0 + p1, 0.f) * w[j];
            acc[1][0] += fmaxf(a1 + p0, 0.f) * w[j];
            acc[1][1] += fmaxf(a1 + p1, 0.f) * w[j];
        }
    }
    float bq = bq2[0];
#pragma unroll
    for (int r = 0; r < 2; r++) {
        int u = ub + uu * 2 + r;
        float2 o;
        o.x = 1.f / (1.f + __expf(-(acc[r][0] + bq)));
        o.y = 1.f / (1.f + __expf(-(acc[r][1] + bq)));
        *(float2*)&out[(size_t)u * Pc + pb + pp * 2] = o;
    }
}

// ---------------- launcher ----------------

extern "C" void kernel_launch(void* const* d_in, const int* in_sizes, int n_in,
                              void* d_out, int out_size, void* d_ws, size_t ws_size,
                              hipStream_t stream) {
    const int*   uid = (const int*)d_in[0];
    const int*   pid = (const int*)d_in[1];
    const int*   ei  = (const int*)d_in[2];   // [2,E]: src = ei[0..E), dst = ei[E..2E)
    const float* ue  = (const float*)d_in[4];
    const float* pe  = (const float*)d_in[5];
    const float* W0  = (const float*)d_in[6];  const float* b0 = (const float*)d_in[7];
    const float* W1  = (const float*)d_in[8];  const float* b1 = (const float*)d_in[9];
    const float* W2  = (const float*)d_in[10]; const float* b2 = (const float*)d_in[11];
    const float* Wu  = (const float*)d_in[12]; const float* bu = (const float*)d_in[13];
    const float* Wp  = (const float*)d_in[14]; const float* bp = (const float*)d_in[15];
    const float* Wq1 = (const float*)d_in[16]; const float* bq1 = (const float*)d_in[17];
    const float* Wq2 = (const float*)d_in[18]; const float* bq2 = (const float*)d_in[19];

    const int* e_src = ei;
    const int* e_dst = ei + Ec;

    char* w = (char*)d_ws;
    auto alloc = [&](size_t bytes) { char* p = w; w += (bytes + 255) & ~size_t(255); return p; };
    int*            cnt  = (int*)alloc(Nc * 4);
    unsigned short* colF = (unsigned short*)alloc((size_t)Nc * CAP * 2);
    float* xA   = (float*)alloc((size_t)Nc * Hc * 4);
    float* xB   = (float*)alloc((size_t)Nc * Hc * 4);
    float* Wup  = (float*)alloc((size_t)Hc * Hc * 4);
    float* Wpp  = (float*)alloc((size_t)Hc * Hc * 4);
    float* bvu  = (float*)alloc(Hc * 4);
    float* bvp  = (float*)alloc(Hc * 4);
    float* AuT  = (float*)alloc((size_t)Hc * Uc * 4);
    float* ApT  = (float*)alloc((size_t)Hc * Pc * 4);
    float* pred = (float*)d_out;

    // 0: zero bucket counters (tiny DMA)
    hipMemsetAsync(cnt, 0, Nc * 4, stream);
    // 1: scatter | weight collapse | bias collapse
    k_front<<<642, 256, 0, stream>>>(e_src, e_dst, cnt, colF, Wu, Wp, Wq1,
                                     bu, bp, bq1, Wup, Wpp, bvu, bvp);
    // 2-4: fused GCN layers (r12 structure; colF packed to u16)
    k_l0<<<Nc / 2, 256, 0, stream>>>(uid, pid, ue, pe, W0, b0, cnt, colF, xA);
    k_lh<<<Nc / 2, 256, 0, stream>>>(xA, W1, b1, cnt, colF, xB);
    k_lht<<<Nc / 2, 256, 0, stream>>>(xB, W2, b2, cnt, colF, Wup, Wpp, bvu, bvp, AuT, ApT);
    // 5: predictor
    k_pred<<<dim3(Uc / 16, Pc / 64), 256, 0, stream>>>(AuT, ApT, Wq2, bq2, pred);
}